// Round 6
// baseline (981.618 us; speedup 1.0000x reference)
//
#include <hip/hip_runtime.h>
#include <hip/hip_bf16.h>

// Problem constants (match reference)
constexpr int B = 8192;
constexpr int G = 1024;
constexpr int E = 256;
constexpr int K = 2048;
constexpr float P_NULL = 0.1f;
constexpr int N_STEP = 4;

typedef unsigned short u16;
typedef short bf16x8 __attribute__((ext_vector_type(8)));
typedef float f32x4 __attribute__((ext_vector_type(4)));

// ---------------------------------------------------------------------------
// bf16 <-> f32 (RNE)
// ---------------------------------------------------------------------------
__device__ inline u16 f2bf(float f) {
    union { float f; uint32_t u; } cv;
    cv.f = f;
    const uint32_t u = cv.u;
    return (u16)((u + 0x7fffu + ((u >> 16) & 1u)) >> 16);
}
__device__ inline float bf2f(u16 h) {
    union { uint32_t u; float f; } cv;
    cv.u = ((uint32_t)h) << 16;
    return cv.f;
}
__device__ inline uint4 pack8(const float* v) {
    uint4 u;
    u.x = (uint32_t)f2bf(v[0]) | ((uint32_t)f2bf(v[1]) << 16);
    u.y = (uint32_t)f2bf(v[2]) | ((uint32_t)f2bf(v[3]) << 16);
    u.z = (uint32_t)f2bf(v[4]) | ((uint32_t)f2bf(v[5]) << 16);
    u.w = (uint32_t)f2bf(v[6]) | ((uint32_t)f2bf(v[7]) << 16);
    return u;
}

// async global->LDS, 16B per lane (uniform base + lane*16)
typedef __attribute__((address_space(1))) const void* gaddr_t;
typedef __attribute__((address_space(3))) void* laddr_t;
__device__ inline void gload_lds16(const void* g, void* l) {
    __builtin_amdgcn_global_load_lds((gaddr_t)g, (laddr_t)l, 16, 0, 0);
}

// XCD-aware tile swizzle (requires gridDim.y % 8 == 0)
__device__ inline void swizzle_tiles(int& tr, int& tc) {
    const int cx = gridDim.x, cy = gridDim.y;
    const int id = blockIdx.y * cx + blockIdx.x;
    const int k = id & 7;
    const int q = id >> 3;
    tr = k * (cy >> 3) + q / cx;
    tc = q % cx;
}

// ---------------------------------------------------------------------------
// f2bf flat convert, 8 elems/thread
// ---------------------------------------------------------------------------
__global__ __launch_bounds__(256) void f2bf_kernel(
    const float* __restrict__ in, u16* __restrict__ out, int n) {
    const int i = (blockIdx.x * 256 + threadIdx.x) * 8;
    if (i + 7 >= n) {
        for (int j = i; j < n; ++j) out[j] = f2bf(in[j]);
        return;
    }
    const float4 a = *(const float4*)(in + i);
    const float4 b = *(const float4*)(in + i + 4);
    float v[8] = {a.x, a.y, a.z, a.w, b.x, b.y, b.z, b.w};
    *(uint4*)(out + i) = pack8(v);
}

// ---------------------------------------------------------------------------
// f32 (R,C) -> bf16 (C,R) transpose. grid (C/32, R/32), block 256.
// ---------------------------------------------------------------------------
__global__ __launch_bounds__(256) void transpose_bf_kernel(
    const float* __restrict__ in, u16* __restrict__ out, int R, int C) {
    __shared__ float tile[32][33];
    const int bx = blockIdx.x * 32, by = blockIdx.y * 32;
    const int x = threadIdx.x & 31, y0 = threadIdx.x >> 5;
#pragma unroll
    for (int yy = 0; yy < 32; yy += 8)
        tile[y0 + yy][x] = in[(size_t)(by + y0 + yy) * C + bx + x];
    __syncthreads();
#pragma unroll
    for (int yy = 0; yy < 32; yy += 8)
        out[(size_t)(bx + y0 + yy) * R + by + x] = f2bf(tile[x][y0 + yy]);
}

// ---------------------------------------------------------------------------
// Column mean-of-squares (f32 in): out[k] += inv_rows * sum_r M[r,k]^2
// ---------------------------------------------------------------------------
__global__ __launch_bounds__(256) void colsq_kernel(
    const float* __restrict__ M, int rows, int cols, float inv_rows,
    float* __restrict__ out) {
    const int k = blockIdx.x * 256 + threadIdx.x;
    const int r0 = blockIdx.y * 128;
    const int r1 = min(r0 + 128, rows);
    float s = 0.f;
    for (int r = r0; r < r1; ++r) {
        const float v = M[(size_t)r * cols + k];
        s = fmaf(v, v, s);
    }
    atomicAdd(out + k, s * inv_rows);
}

// ---------------------------------------------------------------------------
// MFMA bf16 GEMM (128x128 tile): C = A(M,Kd) x Bm(N,Kd)^T
// used for encode (bias epilogue) and loss (MSE epilogue).
// ---------------------------------------------------------------------------
enum { EPI_BIAS_BF16 = 0, EPI_LOSS = 2 };
constexpr int STG = 136;

template <int EPI>
__global__ __launch_bounds__(256) void mfma_gemm_kernel(
    const u16* __restrict__ A, const u16* __restrict__ Bm,
    void* __restrict__ Cout, const float* __restrict__ bias,
    const float* __restrict__ X, int M, int N, int Kd, float alpha) {
    __shared__ u16 smem[17408];
    u16* As = smem;
    u16* Bs = smem + 8192;
    const int tid = threadIdx.x;
    int btr, btc;
    swizzle_tiles(btr, btc);
    const int row0 = btr * 128, col0 = btc * 128;
    const int lane = tid & 63, wave = tid >> 6;
    const int wr = (wave >> 1) * 64, wc = (wave & 1) * 64;
    const int tx = lane & 15, quad = lane >> 4;

    f32x4 acc[4][4] = {};

    for (int k0 = 0; k0 < Kd; k0 += 64) {
#pragma unroll
        for (int l = 0; l < 4; ++l) {
            const int lin = l * 2048 + tid * 8;
            const int r = lin >> 6, c = lin & 63;
            gload_lds16(A + (size_t)(row0 + r) * Kd + k0 + c, &As[lin]);
        }
#pragma unroll
        for (int l = 0; l < 4; ++l) {
            const int lin = l * 2048 + tid * 8;
            const int r = lin >> 6, c = lin & 63;
            gload_lds16(Bm + (size_t)(col0 + r) * Kd + k0 + c, &Bs[lin]);
        }
        __syncthreads();
#pragma unroll
        for (int ks = 0; ks < 2; ++ks) {
            bf16x8 af[4], bfr[4];
#pragma unroll
            for (int i = 0; i < 4; ++i)
                af[i] = *(const bf16x8*)&As[(wr + i * 16 + tx) * 64 + ks * 32 + quad * 8];
#pragma unroll
            for (int j = 0; j < 4; ++j)
                bfr[j] = *(const bf16x8*)&Bs[(wc + j * 16 + tx) * 64 + ks * 32 + quad * 8];
#pragma unroll
            for (int i = 0; i < 4; ++i)
#pragma unroll
                for (int j = 0; j < 4; ++j)
                    acc[i][j] = __builtin_amdgcn_mfma_f32_16x16x32_bf16(
                        af[i], bfr[j], acc[i][j], 0, 0, 0);
        }
        __syncthreads();
    }

    // C/D layout (m89): col = lane&15, row = (lane>>4)*4 + reg
    if (EPI == EPI_LOSS) {
        float* loss = (float*)Cout;
        const float inv_n = 1.0f / (float)N;
#pragma unroll
        for (int i = 0; i < 4; ++i) {
#pragma unroll
            for (int r = 0; r < 4; ++r) {
                const int row = row0 + wr + i * 16 + quad * 4 + r;
                float s = 0.f;
#pragma unroll
                for (int j = 0; j < 4; ++j) {
                    const int col = col0 + wc + j * 16 + tx;
                    const float d = acc[i][j][r] - X[(size_t)row * N + col];
                    s = fmaf(d, d, s);
                }
                s += __shfl_xor(s, 1, 64);
                s += __shfl_xor(s, 2, 64);
                s += __shfl_xor(s, 4, 64);
                s += __shfl_xor(s, 8, 64);
                if (tx == 0) atomicAdd(&loss[row], s * inv_n);
            }
        }
    } else {
        u16* C = (u16*)Cout;
#pragma unroll
        for (int i = 0; i < 4; ++i)
#pragma unroll
            for (int j = 0; j < 4; ++j) {
                const int col = wc + j * 16 + tx;
                const float b = bias[col0 + col];
#pragma unroll
                for (int r = 0; r < 4; ++r) {
                    const int row = wr + i * 16 + quad * 4 + r;
                    smem[row * STG + col] = f2bf(fmaf(acc[i][j][r], alpha, -b));
                }
            }
        __syncthreads();
        const int rr = tid >> 1, half = (tid & 1) * 64;
#pragma unroll
        for (int u = 0; u < 8; ++u) {
            *(uint4*)(C + (size_t)(row0 + rr) * N + col0 + half + u * 8) =
                *(const uint4*)&smem[rr * STG + half + u * 8];
        }
    }
}

// ---------------------------------------------------------------------------
// FUSED band kernel (16 B-rows per block, 256 thr = 4 waves).
//  MODE_ENCODE:   stage t(B,K); pik = softmax(t) -> OutBK; z = pik@xb^T -> OutZ
//  MODE_REWEIGHT: t = z@xbT*(2/E)-c2b in regs; xp = pik*exp(t-m)/sum (LDS only);
//                 z' = xp@xb^T -> OutZ
//  MODE_DECODE:   t as above; xq = exp(t-x2)/(P_NULL+sum) -> OutBK
// xp/pik/xq live in padded LDS (PSTR = 2048+8 breaks bank conflicts, keeps
// 16B alignment; global_load_lds staged ROW BY ROW so padding is safe).
// ---------------------------------------------------------------------------
enum { MODE_ENCODE = 0, MODE_REWEIGHT = 1, MODE_DECODE = 2 };
constexpr int PSTR = 2056;  // u16 row stride of Ps
constexpr int ZSTR = 264;   // u16 row stride of Zs

template <int MODE>
__global__ __launch_bounds__(256) void fused_band_kernel(
    const u16* __restrict__ ZorT,  // REWEIGHT/DECODE: z (B,E); ENCODE: t (B,K)
    const u16* __restrict__ XbT,   // (K,E) bf16  (GEMM1 B)
    const u16* __restrict__ c2bh,  // (K) bf16 bias
    const u16* __restrict__ Pik,   // (B,K) bf16  (REWEIGHT)
    const u16* __restrict__ Xb,    // (E,K) bf16  (GEMM2 B)
    u16* __restrict__ OutBK,       // ENCODE: pik; DECODE: xq
    u16* __restrict__ OutZ) {      // ENCODE/REWEIGHT: z out (B,E)
    __shared__ u16 Ps[16 * PSTR];  // 65792 B
    __shared__ u16 Zs[16 * ZSTR];  // 8448 B
    __shared__ u16 c2s[K];         // 4096 B
    __shared__ float red_m[4][16];
    __shared__ float red_s[4][16];
    __shared__ float rowx2[16];
    const int tid = threadIdx.x;
    const int lane = tid & 63, wave = tid >> 6;
    const int tx = lane & 15, quad = lane >> 4;
    const int row0 = blockIdx.x * 16;
    const int kw = wave * 512;

    // ---------------- staging ----------------
    if (MODE == MODE_ENCODE) {
#pragma unroll
        for (int rr = 0; rr < 16; ++rr)
            gload_lds16(ZorT + (size_t)(row0 + rr) * K + tid * 8, &Ps[rr * PSTR + tid * 8]);
    } else {
        if (MODE == MODE_REWEIGHT) {
#pragma unroll
            for (int rr = 0; rr < 16; ++rr)
                gload_lds16(Pik + (size_t)(row0 + rr) * K + tid * 8, &Ps[rr * PSTR + tid * 8]);
        }
        gload_lds16(c2bh + tid * 8, &c2s[tid * 8]);
        // z band -> padded Zs via registers (pad breaks global_load_lds linearity)
        {
            const int r = tid >> 4, c0 = (tid & 15) * 16;
            const uint4 a = *(const uint4*)(ZorT + (size_t)(row0 + r) * E + c0);
            const uint4 b = *(const uint4*)(ZorT + (size_t)(row0 + r) * E + c0 + 8);
            *(uint4*)&Zs[r * ZSTR + c0] = a;
            *(uint4*)&Zs[r * ZSTR + c0 + 8] = b;
        }
    }
    __syncthreads();

    f32x4 acc[32];

    if (MODE == MODE_ENCODE) {
        // load t into C-layout regs (2-way LDS reads thanks to pad)
#pragma unroll
        for (int c = 0; c < 32; ++c)
#pragma unroll
            for (int r = 0; r < 4; ++r)
                acc[c][r] = bf2f(Ps[(quad * 4 + r) * PSTR + kw + c * 16 + tx]);
    } else {
        // A-frags from Zs (row = tx, k-offset = s*32 + quad*8)
        bf16x8 af[8];
#pragma unroll
        for (int s = 0; s < 8; ++s)
            af[s] = *(const bf16x8*)&Zs[tx * ZSTR + s * 32 + quad * 8];

        if (MODE == MODE_DECODE) {
            float s2 = 0.f;
#pragma unroll
            for (int s = 0; s < 8; ++s)
#pragma unroll
                for (int j = 0; j < 8; ++j) {
                    const float zv = bf2f((u16)af[s][j]);
                    s2 = fmaf(zv, zv, s2);
                }
            s2 += __shfl_xor(s2, 16, 64);
            s2 += __shfl_xor(s2, 32, 64);
            if (wave == 0 && quad == 0) rowx2[tx] = s2 * (1.0f / (float)E);
        }

        // GEMM1: 32 k-frags, B streamed from L2-resident XbT
#pragma unroll
        for (int c = 0; c < 32; ++c) {
            f32x4 a = {0.f, 0.f, 0.f, 0.f};
            const u16* bp = XbT + (size_t)(kw + c * 16 + tx) * E + quad * 8;
#pragma unroll
            for (int s = 0; s < 8; ++s) {
                const bf16x8 bfr = *(const bf16x8*)(bp + s * 32);
                a = __builtin_amdgcn_mfma_f32_16x16x32_bf16(af[s], bfr, a, 0, 0, 0);
            }
            acc[c] = a;
        }
        const float ascale = 2.0f / (float)E;
#pragma unroll
        for (int c = 0; c < 32; ++c) {
            const float cb = bf2f(c2s[kw + c * 16 + tx]);
#pragma unroll
            for (int r = 0; r < 4; ++r)
                acc[c][r] = fmaf(acc[c][r], ascale, -cb);
        }
    }

    // ---------------- row max ----------------
    float mrow[4] = {-1e30f, -1e30f, -1e30f, -1e30f};
#pragma unroll
    for (int c = 0; c < 32; ++c)
#pragma unroll
        for (int r = 0; r < 4; ++r) mrow[r] = fmaxf(mrow[r], acc[c][r]);
#pragma unroll
    for (int r = 0; r < 4; ++r) {
        mrow[r] = fmaxf(mrow[r], __shfl_xor(mrow[r], 1, 64));
        mrow[r] = fmaxf(mrow[r], __shfl_xor(mrow[r], 2, 64));
        mrow[r] = fmaxf(mrow[r], __shfl_xor(mrow[r], 4, 64));
        mrow[r] = fmaxf(mrow[r], __shfl_xor(mrow[r], 8, 64));
    }
    if (tx == 0) {
#pragma unroll
        for (int r = 0; r < 4; ++r) red_m[wave][quad * 4 + r] = mrow[r];
    }
    __syncthreads();
    float M[4];
#pragma unroll
    for (int r = 0; r < 4; ++r) {
        const int row = quad * 4 + r;
        M[r] = fmaxf(fmaxf(red_m[0][row], red_m[1][row]),
                     fmaxf(red_m[2][row], red_m[3][row]));
    }

    // ---------------- exp (* pik) + row sum ----------------
    float srow[4] = {0.f, 0.f, 0.f, 0.f};
#pragma unroll
    for (int c = 0; c < 32; ++c)
#pragma unroll
        for (int r = 0; r < 4; ++r) {
            float w = __expf(acc[c][r] - M[r]);
            if (MODE == MODE_REWEIGHT)
                w *= bf2f(Ps[(quad * 4 + r) * PSTR + kw + c * 16 + tx]);
            acc[c][r] = w;
            srow[r] += w;
        }
#pragma unroll
    for (int r = 0; r < 4; ++r) {
        srow[r] += __shfl_xor(srow[r], 1, 64);
        srow[r] += __shfl_xor(srow[r], 2, 64);
        srow[r] += __shfl_xor(srow[r], 4, 64);
        srow[r] += __shfl_xor(srow[r], 8, 64);
    }
    if (tx == 0) {
#pragma unroll
        for (int r = 0; r < 4; ++r) red_s[wave][quad * 4 + r] = srow[r];
    }
    __syncthreads();

    float F[4];
#pragma unroll
    for (int r = 0; r < 4; ++r) {
        const int row = quad * 4 + r;
        const float S = red_s[0][row] + red_s[1][row] + red_s[2][row] + red_s[3][row];
        if (MODE == MODE_DECODE) {
            const float em = __expf(M[r] - rowx2[row]);
            F[r] = em / (P_NULL + em * S);
        } else {
            F[r] = 1.0f / S;
        }
    }

    // ---------------- write normalized weights to Ps ----------------
#pragma unroll
    for (int c = 0; c < 32; ++c)
#pragma unroll
        for (int r = 0; r < 4; ++r)
            Ps[(quad * 4 + r) * PSTR + kw + c * 16 + tx] = f2bf(acc[c][r] * F[r]);
    __syncthreads();

    if (MODE != MODE_REWEIGHT) {
        // coalesced copy Ps -> OutBK (pik or xq)
#pragma unroll
        for (int rr = 0; rr < 16; ++rr)
            *(uint4*)(OutBK + (size_t)(row0 + rr) * K + tid * 8) =
                *(const uint4*)&Ps[rr * PSTR + tid * 8];
    }

    if (MODE != MODE_DECODE) {
        // GEMM2: z' = w @ Xb^T  (wave owns e-cols [wave*64, wave*64+64))
        f32x4 acc2[4] = {};
        const int e0 = wave * 64;
        for (int ks = 0; ks < 64; ++ks) {
            const bf16x8 a2 = *(const bf16x8*)&Ps[tx * PSTR + ks * 32 + quad * 8];
#pragma unroll
            for (int f = 0; f < 4; ++f) {
                const bf16x8 b2 = *(const bf16x8*)
                    &Xb[(size_t)(e0 + f * 16 + tx) * K + ks * 32 + quad * 8];
                acc2[f] = __builtin_amdgcn_mfma_f32_16x16x32_bf16(a2, b2, acc2[f], 0, 0, 0);
            }
        }
        // repack z through Zs, coalesced store
#pragma unroll
        for (int f = 0; f < 4; ++f)
#pragma unroll
            for (int r = 0; r < 4; ++r)
                Zs[(quad * 4 + r) * ZSTR + e0 + f * 16 + tx] = f2bf(acc2[f][r]);
        __syncthreads();
        const int r = tid >> 4, c0 = (tid & 15) * 16;
        *(uint4*)(OutZ + (size_t)(row0 + r) * E + c0) = *(const uint4*)&Zs[r * ZSTR + c0];
        *(uint4*)(OutZ + (size_t)(row0 + r) * E + c0 + 8) =
            *(const uint4*)&Zs[r * ZSTR + c0 + 8];
    }
}

// ---------------------------------------------------------------------------
extern "C" void kernel_launch(void* const* d_in, const int* in_sizes, int n_in,
                              void* d_out, int out_size, void* d_ws, size_t ws_size,
                              hipStream_t stream) {
    const float* images = (const float*)d_in[0];  // (B,G)
    const float* xa     = (const float*)d_in[1];  // (G,K)
    const float* xb     = (const float*)d_in[2];  // (E,K)
    float* out = (float*)d_out;                   // (B,)

    // workspace carve-up (u16 elements, 16B-aligned regions)
    u16* img_bf  = (u16*)d_ws;                      // B*G
    u16* xa_bf   = img_bf + (size_t)B * G;          // G*K
    u16* xaT_bf  = xa_bf + (size_t)G * K;           // K*G
    u16* xb_bf   = xaT_bf + (size_t)K * G;          // E*K
    u16* xbT_bf  = xb_bf + (size_t)E * K;           // K*E
    u16* pik_bf  = xbT_bf + (size_t)K * E;          // B*K
    u16* t_bf    = pik_bf + (size_t)B * K;          // B*K
    u16* xq_bf   = t_bf + (size_t)B * K;            // B*K
    u16* z0_bf   = xq_bf + (size_t)B * K;           // B*E
    u16* z1_bf   = z0_bf + (size_t)B * E;           // B*E
    u16* c2b_bf  = z1_bf + (size_t)B * E;           // K
    float* c2a   = (float*)(c2b_bf + K);            // K
    float* c2b   = c2a + K;                         // K

    (void)hipMemsetAsync(d_out, 0, (size_t)B * sizeof(float), stream);
    (void)hipMemsetAsync(c2a, 0, (size_t)2 * K * sizeof(float), stream);

    // bf16 conversions + transposes
    f2bf_kernel<<<(B * G) / 2048, 256, 0, stream>>>(images, img_bf, B * G);
    f2bf_kernel<<<(G * K) / 2048, 256, 0, stream>>>(xa, xa_bf, G * K);
    f2bf_kernel<<<(E * K) / 2048, 256, 0, stream>>>(xb, xb_bf, E * K);
    transpose_bf_kernel<<<dim3(K / 32, G / 32), 256, 0, stream>>>(xa, xaT_bf, G, K);
    transpose_bf_kernel<<<dim3(K / 32, E / 32), 256, 0, stream>>>(xb, xbT_bf, E, K);

    // c2a[k] = mean_g xa[g,k]^2 (f32, for encode GEMM) ; c2b likewise -> bf16
    colsq_kernel<<<dim3(K / 256, G / 128), 256, 0, stream>>>(xa, G, K, 1.0f / G, c2a);
    colsq_kernel<<<dim3(K / 256, E / 128), 256, 0, stream>>>(xb, E, K, 1.0f / E, c2b);
    f2bf_kernel<<<1, 256, 0, stream>>>(c2b, c2b_bf, K);

    // encode: t = images@xa * (2/G) - c2a
    mfma_gemm_kernel<EPI_BIAS_BF16><<<dim3(K / 128, B / 128), 256, 0, stream>>>(
        img_bf, xaT_bf, t_bf, c2a, nullptr, B, K, G, 2.0f / (float)G);

    // fused: pik = softmax(t) ; z0 = pik @ xb^T
    fused_band_kernel<MODE_ENCODE><<<B / 16, 256, 0, stream>>>(
        t_bf, nullptr, nullptr, nullptr, xb_bf, pik_bf, z0_bf);

    // loop: z ping-pongs z0 -> z1 -> z0 -> z1 -> z0
    u16* zin = z0_bf;
    u16* zout = z1_bf;
    for (int s = 0; s < N_STEP; ++s) {
        fused_band_kernel<MODE_REWEIGHT><<<B / 16, 256, 0, stream>>>(
            zin, xbT_bf, c2b_bf, pik_bf, xb_bf, nullptr, zout);
        u16* tmp = zin; zin = zout; zout = tmp;
    }

    // fused decode: xq = exp(t - x2)/(P_NULL + sum)
    fused_band_kernel<MODE_DECODE><<<B / 16, 256, 0, stream>>>(
        zin, xbT_bf, c2b_bf, nullptr, nullptr, xq_bf, nullptr);

    // recon = xq @ xa^T ; loss[b] = mean_g (recon - images)^2
    mfma_gemm_kernel<EPI_LOSS><<<dim3(G / 128, B / 128), 256, 0, stream>>>(
        xq_bf, xa_bf, out, nullptr, images, B, G, K, 1.0f);
}

// Round 7
// 572.659 us; speedup vs baseline: 1.7141x; 1.7141x over previous
//
#include <hip/hip_runtime.h>
#include <hip/hip_bf16.h>

// Problem constants (match reference)
constexpr int B = 8192;
constexpr int G = 1024;
constexpr int E = 256;
constexpr int K = 2048;
constexpr float P_NULL = 0.1f;
constexpr int N_STEP = 4;

typedef unsigned short u16;
typedef short bf16x8 __attribute__((ext_vector_type(8)));
typedef float f32x4 __attribute__((ext_vector_type(4)));

// ---------------------------------------------------------------------------
// bf16 <-> f32 (RNE)
// ---------------------------------------------------------------------------
__device__ inline u16 f2bf(float f) {
    union { float f; uint32_t u; } cv;
    cv.f = f;
    const uint32_t u = cv.u;
    return (u16)((u + 0x7fffu + ((u >> 16) & 1u)) >> 16);
}
__device__ inline float bf2f(u16 h) {
    union { uint32_t u; float f; } cv;
    cv.u = ((uint32_t)h) << 16;
    return cv.f;
}
__device__ inline void unpack8(uint4 u, float* v) {
    v[0] = bf2f((u16)(u.x & 0xffff)); v[1] = bf2f((u16)(u.x >> 16));
    v[2] = bf2f((u16)(u.y & 0xffff)); v[3] = bf2f((u16)(u.y >> 16));
    v[4] = bf2f((u16)(u.z & 0xffff)); v[5] = bf2f((u16)(u.z >> 16));
    v[6] = bf2f((u16)(u.w & 0xffff)); v[7] = bf2f((u16)(u.w >> 16));
}
__device__ inline uint4 pack8(const float* v) {
    uint4 u;
    u.x = (uint32_t)f2bf(v[0]) | ((uint32_t)f2bf(v[1]) << 16);
    u.y = (uint32_t)f2bf(v[2]) | ((uint32_t)f2bf(v[3]) << 16);
    u.z = (uint32_t)f2bf(v[4]) | ((uint32_t)f2bf(v[5]) << 16);
    u.w = (uint32_t)f2bf(v[6]) | ((uint32_t)f2bf(v[7]) << 16);
    return u;
}

// async global->LDS, 16B per lane (LDS dest is lane-linear; global src is
// per-lane and may be permuted -> we XOR-swizzle on the global side)
typedef __attribute__((address_space(1))) const void* gaddr_t;
typedef __attribute__((address_space(3))) void* laddr_t;
__device__ inline void gload_lds16(const void* g, void* l) {
    __builtin_amdgcn_global_load_lds((gaddr_t)g, (laddr_t)l, 16, 0, 0);
}

// XCD-aware tile swizzle (requires gridDim.y % 8 == 0)
__device__ inline void swizzle_tiles(int& tr, int& tc) {
    const int cx = gridDim.x, cy = gridDim.y;
    const int id = blockIdx.y * cx + blockIdx.x;
    const int k = id & 7;
    const int q = id >> 3;
    tr = k * (cy >> 3) + q / cx;
    tc = q % cx;
}

// ---------------------------------------------------------------------------
// Reduction helpers (256-thread blocks, wave64)
// ---------------------------------------------------------------------------
__device__ inline float wave_sum(float v) {
#pragma unroll
    for (int off = 32; off > 0; off >>= 1) v += __shfl_down(v, off, 64);
    return v;
}
__device__ inline float wave_max(float v) {
#pragma unroll
    for (int off = 32; off > 0; off >>= 1) v = fmaxf(v, __shfl_down(v, off, 64));
    return v;
}
__device__ inline float block_sum256(float v, float* sm) {
    v = wave_sum(v);
    const int w = threadIdx.x >> 6;
    if ((threadIdx.x & 63) == 0) sm[w] = v;
    __syncthreads();
    const float r = sm[0] + sm[1] + sm[2] + sm[3];
    __syncthreads();
    return r;
}
__device__ inline float block_max256(float v, float* sm) {
    v = wave_max(v);
    const int w = threadIdx.x >> 6;
    if ((threadIdx.x & 63) == 0) sm[w] = v;
    __syncthreads();
    const float r = fmaxf(fmaxf(sm[0], sm[1]), fmaxf(sm[2], sm[3]));
    __syncthreads();
    return r;
}

// ---------------------------------------------------------------------------
// f32 -> bf16 flat convert, 8 elems/thread
// ---------------------------------------------------------------------------
__global__ __launch_bounds__(256) void f2bf_kernel(
    const float* __restrict__ in, u16* __restrict__ out, int n) {
    const int i = (blockIdx.x * 256 + threadIdx.x) * 8;
    if (i + 7 >= n) {
        for (int j = i; j < n; ++j) out[j] = f2bf(in[j]);
        return;
    }
    const float4 a = *(const float4*)(in + i);
    const float4 b = *(const float4*)(in + i + 4);
    float v[8] = {a.x, a.y, a.z, a.w, b.x, b.y, b.z, b.w};
    *(uint4*)(out + i) = pack8(v);
}

// ---------------------------------------------------------------------------
// f32 (R,C) -> bf16 (C,R) transpose. grid (C/32, R/32), block 256.
// ---------------------------------------------------------------------------
__global__ __launch_bounds__(256) void transpose_bf_kernel(
    const float* __restrict__ in, u16* __restrict__ out, int R, int C) {
    __shared__ float tile[32][33];
    const int bx = blockIdx.x * 32, by = blockIdx.y * 32;
    const int x = threadIdx.x & 31, y0 = threadIdx.x >> 5;
#pragma unroll
    for (int yy = 0; yy < 32; yy += 8)
        tile[y0 + yy][x] = in[(size_t)(by + y0 + yy) * C + bx + x];
    __syncthreads();
#pragma unroll
    for (int yy = 0; yy < 32; yy += 8)
        out[(size_t)(bx + y0 + yy) * R + by + x] = f2bf(tile[x][y0 + yy]);
}

// ---------------------------------------------------------------------------
// Column mean-of-squares (f32 in): out[k] += inv_rows * sum_r M[r,k]^2
// ---------------------------------------------------------------------------
__global__ __launch_bounds__(256) void colsq_kernel(
    const float* __restrict__ M, int rows, int cols, float inv_rows,
    float* __restrict__ out) {
    const int k = blockIdx.x * 256 + threadIdx.x;
    const int r0 = blockIdx.y * 128;
    const int r1 = min(r0 + 128, rows);
    float s = 0.f;
    for (int r = r0; r < r1; ++r) {
        const float v = M[(size_t)r * cols + k];
        s = fmaf(v, v, s);
    }
    atomicAdd(out + k, s * inv_rows);
}

// ---------------------------------------------------------------------------
// MFMA bf16 GEMM (128x128 tile, BK=64): C = A(M,Kd) x Bm(N,Kd)^T
// LDS layout XOR-swizzled: 16B group g of row r stored at group g^(r&7).
// Swizzle applied on the GLOBAL source address (per-lane); LDS dest stays
// lane-linear as global_load_lds requires. Frag ds_read_b128 then hits 8
// distinct bank groups (2-way = free) instead of 16-way conflicts.
// ---------------------------------------------------------------------------
enum { EPI_BIAS_BF16 = 0, EPI_BF16 = 1, EPI_LOSS = 2 };

template <int EPI>
__global__ __launch_bounds__(256) void mfma_gemm_kernel(
    const u16* __restrict__ A, const u16* __restrict__ Bm,
    void* __restrict__ Cout, const float* __restrict__ bias,
    const float* __restrict__ X, int M, int N, int Kd, float alpha) {
    __shared__ u16 As[128 * 64];
    __shared__ u16 Bs[128 * 64];
    const int tid = threadIdx.x;
    int btr, btc;
    swizzle_tiles(btr, btc);
    const int row0 = btr * 128, col0 = btc * 128;
    const int lane = tid & 63, wave = tid >> 6;
    const int wr = (wave >> 1) * 64, wc = (wave & 1) * 64;
    const int tx = lane & 15, quad = lane >> 4;
    const int txl = tx & 7;  // row&7 for frag rows (wr, i*16 are multiples of 8)

    f32x4 acc[4][4] = {};

    for (int k0 = 0; k0 < Kd; k0 += 64) {
#pragma unroll
        for (int l = 0; l < 4; ++l) {
            const int lin = l * 2048 + tid * 8;
            const int r = lin >> 6;
            const int c = (((lin >> 3) & 7) ^ (r & 7)) * 8;  // swizzled source col
            gload_lds16(A + (size_t)(row0 + r) * Kd + k0 + c, &As[lin]);
        }
#pragma unroll
        for (int l = 0; l < 4; ++l) {
            const int lin = l * 2048 + tid * 8;
            const int r = lin >> 6;
            const int c = (((lin >> 3) & 7) ^ (r & 7)) * 8;
            gload_lds16(Bm + (size_t)(col0 + r) * Kd + k0 + c, &Bs[lin]);
        }
        __syncthreads();
#pragma unroll
        for (int ks = 0; ks < 2; ++ks) {
            bf16x8 af[4], bfr[4];
            const int gsw = ((ks * 4 + quad) ^ txl) * 8;  // swizzled group offset
#pragma unroll
            for (int i = 0; i < 4; ++i)
                af[i] = *(const bf16x8*)&As[(wr + i * 16 + tx) * 64 + gsw];
#pragma unroll
            for (int j = 0; j < 4; ++j)
                bfr[j] = *(const bf16x8*)&Bs[(wc + j * 16 + tx) * 64 + gsw];
#pragma unroll
            for (int i = 0; i < 4; ++i)
#pragma unroll
                for (int j = 0; j < 4; ++j)
                    acc[i][j] = __builtin_amdgcn_mfma_f32_16x16x32_bf16(
                        af[i], bfr[j], acc[i][j], 0, 0, 0);
        }
        __syncthreads();
    }

    // C/D layout (m89): col = lane&15, row = (lane>>4)*4 + reg
    if (EPI == EPI_LOSS) {
        float* loss = (float*)Cout;
        const float inv_n = 1.0f / (float)N;
#pragma unroll
        for (int i = 0; i < 4; ++i) {
#pragma unroll
            for (int r = 0; r < 4; ++r) {
                const int row = row0 + wr + i * 16 + quad * 4 + r;
                float s = 0.f;
#pragma unroll
                for (int j = 0; j < 4; ++j) {
                    const int col = col0 + wc + j * 16 + tx;
                    const float d = acc[i][j][r] - X[(size_t)row * N + col];
                    s = fmaf(d, d, s);
                }
                s += __shfl_xor(s, 1, 64);
                s += __shfl_xor(s, 2, 64);
                s += __shfl_xor(s, 4, 64);
                s += __shfl_xor(s, 8, 64);
                if (tx == 0) atomicAdd(&loss[row], s * inv_n);
            }
        }
    } else {
        u16* C = (u16*)Cout;
#pragma unroll
        for (int i = 0; i < 4; ++i)
#pragma unroll
            for (int j = 0; j < 4; ++j) {
                const int col = wc + j * 16 + tx;
                float b = (EPI == EPI_BIAS_BF16) ? bias[col0 + col] : 0.f;
#pragma unroll
                for (int r = 0; r < 4; ++r) {
                    const int row = wr + i * 16 + quad * 4 + r;
                    float v = acc[i][j][r];
                    if (EPI == EPI_BIAS_BF16) v = fmaf(v, alpha, -b);
                    C[(size_t)(row0 + row) * N + col0 + col] = f2bf(v);
                }
            }
    }
}

// ---------------------------------------------------------------------------
// MFMA bf16 GEMM (64x128 tile) for the (B,E)-output GEMMs: 256 blocks.
// Same XOR-swizzled LDS layout.
// ---------------------------------------------------------------------------
__global__ __launch_bounds__(256) void mfma_gemm64_kernel(
    const u16* __restrict__ A, const u16* __restrict__ Bm,
    u16* __restrict__ C, int M, int N, int Kd) {
    __shared__ u16 As[64 * 64];
    __shared__ u16 Bs[128 * 64];
    const int tid = threadIdx.x;
    int btr, btc;
    swizzle_tiles(btr, btc);
    const int row0 = btr * 64, col0 = btc * 128;
    const int lane = tid & 63, wave = tid >> 6;
    const int wr = (wave >> 1) * 32, wc = (wave & 1) * 64;
    const int tx = lane & 15, quad = lane >> 4;
    const int txl = tx & 7;

    f32x4 acc[2][4] = {};

    for (int k0 = 0; k0 < Kd; k0 += 64) {
#pragma unroll
        for (int l = 0; l < 2; ++l) {
            const int lin = l * 2048 + tid * 8;
            const int r = lin >> 6;
            const int c = (((lin >> 3) & 7) ^ (r & 7)) * 8;
            gload_lds16(A + (size_t)(row0 + r) * Kd + k0 + c, &As[lin]);
        }
#pragma unroll
        for (int l = 0; l < 4; ++l) {
            const int lin = l * 2048 + tid * 8;
            const int r = lin >> 6;
            const int c = (((lin >> 3) & 7) ^ (r & 7)) * 8;
            gload_lds16(Bm + (size_t)(col0 + r) * Kd + k0 + c, &Bs[lin]);
        }
        __syncthreads();
#pragma unroll
        for (int ks = 0; ks < 2; ++ks) {
            bf16x8 af[2], bfr[4];
            const int gsw = ((ks * 4 + quad) ^ txl) * 8;
#pragma unroll
            for (int i = 0; i < 2; ++i)
                af[i] = *(const bf16x8*)&As[(wr + i * 16 + tx) * 64 + gsw];
#pragma unroll
            for (int j = 0; j < 4; ++j)
                bfr[j] = *(const bf16x8*)&Bs[(wc + j * 16 + tx) * 64 + gsw];
#pragma unroll
            for (int i = 0; i < 2; ++i)
#pragma unroll
                for (int j = 0; j < 4; ++j)
                    acc[i][j] = __builtin_amdgcn_mfma_f32_16x16x32_bf16(
                        af[i], bfr[j], acc[i][j], 0, 0, 0);
        }
        __syncthreads();
    }

#pragma unroll
    for (int i = 0; i < 2; ++i)
#pragma unroll
        for (int j = 0; j < 4; ++j)
#pragma unroll
            for (int r = 0; r < 4; ++r) {
                const int row = row0 + wr + i * 16 + quad * 4 + r;
                const int col = col0 + wc + j * 16 + tx;
                C[(size_t)row * N + col] = f2bf(acc[i][j][r]);
            }
}

// ---------------------------------------------------------------------------
// Row softmax over K=2048 (bf16 in/out). One block (256 thr) per row.
// ---------------------------------------------------------------------------
__global__ __launch_bounds__(256) void softmax_bf_kernel(
    const u16* __restrict__ T, u16* __restrict__ P) {
    __shared__ float sm[4];
    const size_t base = (size_t)blockIdx.x * K + (size_t)threadIdx.x * 8;
    float v[8];
    unpack8(*(const uint4*)(T + base), v);
    float m = v[0];
#pragma unroll
    for (int i = 1; i < 8; ++i) m = fmaxf(m, v[i]);
    m = block_max256(m, sm);
    float s = 0.f;
#pragma unroll
    for (int i = 0; i < 8; ++i) {
        v[i] = __expf(v[i] - m);
        s += v[i];
    }
    s = block_sum256(s, sm);
    const float inv = 1.f / s;
#pragma unroll
    for (int i = 0; i < 8; ++i) v[i] *= inv;
    *(uint4*)(P + base) = pack8(v);
}

// ---------------------------------------------------------------------------
// Loop reweight: XP = pik*exp(t - rowmax); XP /= rowsum  (bf16 in/out)
// ---------------------------------------------------------------------------
__global__ __launch_bounds__(256) void reweight_bf_kernel(
    const u16* __restrict__ T, const u16* __restrict__ P,
    u16* __restrict__ XP) {
    __shared__ float sm[4];
    const size_t base = (size_t)blockIdx.x * K + (size_t)threadIdx.x * 8;
    float v[8], p[8];
    unpack8(*(const uint4*)(T + base), v);
    unpack8(*(const uint4*)(P + base), p);
    float m = v[0];
#pragma unroll
    for (int i = 1; i < 8; ++i) m = fmaxf(m, v[i]);
    m = block_max256(m, sm);
    float s = 0.f;
#pragma unroll
    for (int i = 0; i < 8; ++i) {
        v[i] = p[i] * __expf(v[i] - m);
        s += v[i];
    }
    s = block_sum256(s, sm);
    const float inv = 1.f / s;
#pragma unroll
    for (int i = 0; i < 8; ++i) v[i] *= inv;
    *(uint4*)(XP + base) = pack8(v);
}

// ---------------------------------------------------------------------------
// Row mean of squares of Z (B,E) bf16: x2[row] = mean(Z[row,:]^2)
// ---------------------------------------------------------------------------
__global__ __launch_bounds__(256) void rowmeansq_bf_kernel(
    const u16* __restrict__ Z, float* __restrict__ out) {
    __shared__ float sm[4];
    const float v = bf2f(Z[(size_t)blockIdx.x * E + threadIdx.x]);
    const float s = block_sum256(v * v, sm);
    if (threadIdx.x == 0) out[blockIdx.x] = s * (1.0f / (float)E);
}

// ---------------------------------------------------------------------------
// Decode: xq = exp(t - x2[row]); XQ = xq / (P_NULL + rowsum(xq))  (bf16)
// ---------------------------------------------------------------------------
__global__ __launch_bounds__(256) void decode_bf_kernel(
    const u16* __restrict__ T, const float* __restrict__ x2z,
    u16* __restrict__ XQ) {
    __shared__ float sm[4];
    const size_t base = (size_t)blockIdx.x * K + (size_t)threadIdx.x * 8;
    const float x2 = x2z[blockIdx.x];
    float v[8];
    unpack8(*(const uint4*)(T + base), v);
    float s = 0.f;
#pragma unroll
    for (int i = 0; i < 8; ++i) {
        v[i] = __expf(v[i] - x2);
        s += v[i];
    }
    s = block_sum256(s, sm);
    const float scale = 1.f / (P_NULL + s);
#pragma unroll
    for (int i = 0; i < 8; ++i) v[i] *= scale;
    *(uint4*)(XQ + base) = pack8(v);
}

// ---------------------------------------------------------------------------
extern "C" void kernel_launch(void* const* d_in, const int* in_sizes, int n_in,
                              void* d_out, int out_size, void* d_ws, size_t ws_size,
                              hipStream_t stream) {
    const float* images = (const float*)d_in[0];  // (B,G)
    const float* xa     = (const float*)d_in[1];  // (G,K)
    const float* xb     = (const float*)d_in[2];  // (E,K)
    float* out = (float*)d_out;                   // (B,)

    // workspace carve-up (u16 elements, all regions 16B-aligned)
    u16* img_bf = (u16*)d_ws;                      // B*G
    u16* xa_bf  = img_bf + (size_t)B * G;          // G*K
    u16* xaT_bf = xa_bf + (size_t)G * K;           // K*G
    u16* xb_bf  = xaT_bf + (size_t)K * G;          // E*K
    u16* xbT_bf = xb_bf + (size_t)E * K;           // K*E
    u16* pik_bf = xbT_bf + (size_t)K * E;          // B*K
    u16* t_bf   = pik_bf + (size_t)B * K;          // B*K
    u16* xp_bf  = t_bf + (size_t)B * K;            // B*K
    u16* z_bf   = xp_bf + (size_t)B * K;           // B*E
    float* x2z  = (float*)(z_bf + (size_t)B * E);  // B
    float* c2a  = x2z + B;                         // K
    float* c2b  = c2a + K;                         // K

    (void)hipMemsetAsync(d_out, 0, (size_t)B * sizeof(float), stream);
    (void)hipMemsetAsync(c2a, 0, (size_t)2 * K * sizeof(float), stream);

    // bf16 conversions + transposes
    f2bf_kernel<<<(B * G) / 2048, 256, 0, stream>>>(images, img_bf, B * G);
    f2bf_kernel<<<(G * K) / 2048, 256, 0, stream>>>(xa, xa_bf, G * K);
    f2bf_kernel<<<(E * K) / 2048, 256, 0, stream>>>(xb, xb_bf, E * K);
    transpose_bf_kernel<<<dim3(K / 32, G / 32), 256, 0, stream>>>(xa, xaT_bf, G, K);
    transpose_bf_kernel<<<dim3(K / 32, E / 32), 256, 0, stream>>>(xb, xbT_bf, E, K);

    // c2a[k] = mean_g xa[g,k]^2 ; c2b[k] = mean_e xb[e,k]^2
    colsq_kernel<<<dim3(K / 256, G / 128), 256, 0, stream>>>(xa, G, K, 1.0f / G, c2a);
    colsq_kernel<<<dim3(K / 256, E / 128), 256, 0, stream>>>(xb, E, K, 1.0f / E, c2b);

    // encode: t = images@xa * (2/G) - c2a
    mfma_gemm_kernel<EPI_BIAS_BF16><<<dim3(K / 128, B / 128), 256, 0, stream>>>(
        img_bf, xaT_bf, t_bf, c2a, nullptr, B, K, G, 2.0f / (float)G);
    softmax_bf_kernel<<<B, 256, 0, stream>>>(t_bf, pik_bf);

    // z = pik @ xb^T
    mfma_gemm64_kernel<<<dim3(E / 128, B / 64), 256, 0, stream>>>(
        pik_bf, xb_bf, z_bf, B, E, K);

    for (int s = 0; s < N_STEP; ++s) {
        // t = z@xb * (2/E) - c2b
        mfma_gemm_kernel<EPI_BIAS_BF16><<<dim3(K / 128, B / 128), 256, 0, stream>>>(
            z_bf, xbT_bf, t_bf, c2b, nullptr, B, K, E, 2.0f / (float)E);
        // xp = pik*exp(t - max) / sum
        reweight_bf_kernel<<<B, 256, 0, stream>>>(t_bf, pik_bf, xp_bf);
        // z = xp @ xb^T
        mfma_gemm64_kernel<<<dim3(E / 128, B / 64), 256, 0, stream>>>(
            xp_bf, xb_bf, z_bf, B, E, K);
    }

    // decode
    rowmeansq_bf_kernel<<<B, 256, 0, stream>>>(z_bf, x2z);
    mfma_gemm_kernel<EPI_BIAS_BF16><<<dim3(K / 128, B / 128), 256, 0, stream>>>(
        z_bf, xbT_bf, t_bf, c2b, nullptr, B, K, E, 2.0f / (float)E);
    decode_bf_kernel<<<B, 256, 0, stream>>>(t_bf, x2z, xp_bf);

    // recon = xq @ xa^T ; loss[b] = mean_g (recon - images)^2
    mfma_gemm_kernel<EPI_LOSS><<<dim3(G / 128, B / 128), 256, 0, stream>>>(
        xp_bf, xa_bf, out, nullptr, images, B, G, K, 1.0f);
}

// Round 8
// 563.244 us; speedup vs baseline: 1.7428x; 1.0167x over previous
//
#include <hip/hip_runtime.h>
#include <hip/hip_bf16.h>

// Problem constants (match reference)
constexpr int B = 8192;
constexpr int G = 1024;
constexpr int E = 256;
constexpr int K = 2048;
constexpr float P_NULL = 0.1f;
constexpr int N_STEP = 4;

typedef unsigned short u16;
typedef short bf16x8 __attribute__((ext_vector_type(8)));
typedef float f32x4 __attribute__((ext_vector_type(4)));

// ---------------------------------------------------------------------------
// bf16 <-> f32 (RNE)
// ---------------------------------------------------------------------------
__device__ inline u16 f2bf(float f) {
    union { float f; uint32_t u; } cv;
    cv.f = f;
    const uint32_t u = cv.u;
    return (u16)((u + 0x7fffu + ((u >> 16) & 1u)) >> 16);
}
__device__ inline float bf2f(u16 h) {
    union { uint32_t u; float f; } cv;
    cv.u = ((uint32_t)h) << 16;
    return cv.f;
}
__device__ inline void unpack8(uint4 u, float* v) {
    v[0] = bf2f((u16)(u.x & 0xffff)); v[1] = bf2f((u16)(u.x >> 16));
    v[2] = bf2f((u16)(u.y & 0xffff)); v[3] = bf2f((u16)(u.y >> 16));
    v[4] = bf2f((u16)(u.z & 0xffff)); v[5] = bf2f((u16)(u.z >> 16));
    v[6] = bf2f((u16)(u.w & 0xffff)); v[7] = bf2f((u16)(u.w >> 16));
}
__device__ inline uint4 pack8(const float* v) {
    uint4 u;
    u.x = (uint32_t)f2bf(v[0]) | ((uint32_t)f2bf(v[1]) << 16);
    u.y = (uint32_t)f2bf(v[2]) | ((uint32_t)f2bf(v[3]) << 16);
    u.z = (uint32_t)f2bf(v[4]) | ((uint32_t)f2bf(v[5]) << 16);
    u.w = (uint32_t)f2bf(v[6]) | ((uint32_t)f2bf(v[7]) << 16);
    return u;
}

// async global->LDS, 16B per lane (LDS dest is lane-linear; global src is
// per-lane and may be permuted -> XOR-swizzle is applied on the GLOBAL side)
typedef __attribute__((address_space(1))) const void* gaddr_t;
typedef __attribute__((address_space(3))) void* laddr_t;
__device__ inline void gload_lds16(const void* g, void* l) {
    __builtin_amdgcn_global_load_lds((gaddr_t)g, (laddr_t)l, 16, 0, 0);
}

// XCD-aware tile swizzle (requires gridDim.y % 8 == 0)
__device__ inline void swizzle_tiles(int& tr, int& tc) {
    const int cx = gridDim.x, cy = gridDim.y;
    const int id = blockIdx.y * cx + blockIdx.x;
    const int k = id & 7;
    const int q = id >> 3;
    tr = k * (cy >> 3) + q / cx;
    tc = q % cx;
}

// ---------------------------------------------------------------------------
// Reduction helpers (256-thread blocks, wave64)
// ---------------------------------------------------------------------------
__device__ inline float wave_sum(float v) {
#pragma unroll
    for (int off = 32; off > 0; off >>= 1) v += __shfl_down(v, off, 64);
    return v;
}
__device__ inline float wave_max(float v) {
#pragma unroll
    for (int off = 32; off > 0; off >>= 1) v = fmaxf(v, __shfl_down(v, off, 64));
    return v;
}
__device__ inline float block_sum256(float v, float* sm) {
    v = wave_sum(v);
    const int w = threadIdx.x >> 6;
    if ((threadIdx.x & 63) == 0) sm[w] = v;
    __syncthreads();
    const float r = sm[0] + sm[1] + sm[2] + sm[3];
    __syncthreads();
    return r;
}
__device__ inline float block_max256(float v, float* sm) {
    v = wave_max(v);
    const int w = threadIdx.x >> 6;
    if ((threadIdx.x & 63) == 0) sm[w] = v;
    __syncthreads();
    const float r = fmaxf(fmaxf(sm[0], sm[1]), fmaxf(sm[2], sm[3]));
    __syncthreads();
    return r;
}

// ---------------------------------------------------------------------------
// f32 -> bf16 flat convert, 8 elems/thread
// ---------------------------------------------------------------------------
__global__ __launch_bounds__(256) void f2bf_kernel(
    const float* __restrict__ in, u16* __restrict__ out, int n) {
    const int i = (blockIdx.x * 256 + threadIdx.x) * 8;
    if (i + 7 >= n) {
        for (int j = i; j < n; ++j) out[j] = f2bf(in[j]);
        return;
    }
    const float4 a = *(const float4*)(in + i);
    const float4 b = *(const float4*)(in + i + 4);
    float v[8] = {a.x, a.y, a.z, a.w, b.x, b.y, b.z, b.w};
    *(uint4*)(out + i) = pack8(v);
}

// ---------------------------------------------------------------------------
// f32 (R,C) -> bf16 (C,R) transpose. grid (C/32, R/32), block 256.
// ---------------------------------------------------------------------------
__global__ __launch_bounds__(256) void transpose_bf_kernel(
    const float* __restrict__ in, u16* __restrict__ out, int R, int C) {
    __shared__ float tile[32][33];
    const int bx = blockIdx.x * 32, by = blockIdx.y * 32;
    const int x = threadIdx.x & 31, y0 = threadIdx.x >> 5;
#pragma unroll
    for (int yy = 0; yy < 32; yy += 8)
        tile[y0 + yy][x] = in[(size_t)(by + y0 + yy) * C + bx + x];
    __syncthreads();
#pragma unroll
    for (int yy = 0; yy < 32; yy += 8)
        out[(size_t)(bx + y0 + yy) * R + by + x] = f2bf(tile[x][y0 + yy]);
}

// ---------------------------------------------------------------------------
// Column mean-of-squares (f32 in): out[k] += inv_rows * sum_r M[r,k]^2
// ---------------------------------------------------------------------------
__global__ __launch_bounds__(256) void colsq_kernel(
    const float* __restrict__ M, int rows, int cols, float inv_rows,
    float* __restrict__ out) {
    const int k = blockIdx.x * 256 + threadIdx.x;
    const int r0 = blockIdx.y * 128;
    const int r1 = min(r0 + 128, rows);
    float s = 0.f;
    for (int r = r0; r < r1; ++r) {
        const float v = M[(size_t)r * cols + k];
        s = fmaf(v, v, s);
    }
    atomicAdd(out + k, s * inv_rows);
}

// ---------------------------------------------------------------------------
// MFMA bf16 GEMM (128x128 tile, BK=64): C = A(M,Kd) x Bm(N,Kd)^T
// LDS XOR-swizzled (16B group g of row r at g^(r&7), applied on the GLOBAL
// source address; frag reads hit 8 distinct bank groups -> 0 conflicts).
// Epilogues (normalizers commute through row-linear GEMMs; exp is
// overflow-safe: logits provably in [-0.1, 0.1]):
//   EPI_BIAS_BF16: bf16 C = alpha*acc - bias[col]
//   EPI_W:  w = pik[row,col]*exp(alpha*acc - bias[col]) -> bf16;
//           Saux[row] += row-sum(w)  (atomic)
//   EPI_U:  u = exp(alpha*acc - bias[col]) -> bf16; Saux[row] += row-sum(u)
//   EPI_LOSS: D = P_NULL*exp(bias[row]) + Saux[row];
//             loss[row] += (1/N)*sum_col (acc/D - X[row,col])^2
// ---------------------------------------------------------------------------
enum { EPI_BIAS_BF16 = 0, EPI_LOSS = 2, EPI_W = 3, EPI_U = 4 };

template <int EPI>
__global__ __launch_bounds__(256) void mfma_gemm_kernel(
    const u16* __restrict__ A, const u16* __restrict__ Bm,
    void* __restrict__ Cout, const float* __restrict__ bias,
    const float* __restrict__ X, const u16* __restrict__ Paux,
    float* __restrict__ Saux, int M, int N, int Kd, float alpha) {
    __shared__ u16 As[128 * 64];
    __shared__ u16 Bs[128 * 64];
    const int tid = threadIdx.x;
    int btr, btc;
    swizzle_tiles(btr, btc);
    const int row0 = btr * 128, col0 = btc * 128;
    const int lane = tid & 63, wave = tid >> 6;
    const int wr = (wave >> 1) * 64, wc = (wave & 1) * 64;
    const int tx = lane & 15, quad = lane >> 4;
    const int txl = tx & 7;

    f32x4 acc[4][4] = {};

    for (int k0 = 0; k0 < Kd; k0 += 64) {
#pragma unroll
        for (int l = 0; l < 4; ++l) {
            const int lin = l * 2048 + tid * 8;
            const int r = lin >> 6;
            const int c = (((lin >> 3) & 7) ^ (r & 7)) * 8;  // XOR-swizzled src col
            gload_lds16(A + (size_t)(row0 + r) * Kd + k0 + c, &As[lin]);
        }
#pragma unroll
        for (int l = 0; l < 4; ++l) {
            const int lin = l * 2048 + tid * 8;
            const int r = lin >> 6;
            const int c = (((lin >> 3) & 7) ^ (r & 7)) * 8;
            gload_lds16(Bm + (size_t)(col0 + r) * Kd + k0 + c, &Bs[lin]);
        }
        __syncthreads();
#pragma unroll
        for (int ks = 0; ks < 2; ++ks) {
            bf16x8 af[4], bfr[4];
            const int gsw = ((ks * 4 + quad) ^ txl) * 8;
#pragma unroll
            for (int i = 0; i < 4; ++i)
                af[i] = *(const bf16x8*)&As[(wr + i * 16 + tx) * 64 + gsw];
#pragma unroll
            for (int j = 0; j < 4; ++j)
                bfr[j] = *(const bf16x8*)&Bs[(wc + j * 16 + tx) * 64 + gsw];
#pragma unroll
            for (int i = 0; i < 4; ++i)
#pragma unroll
                for (int j = 0; j < 4; ++j)
                    acc[i][j] = __builtin_amdgcn_mfma_f32_16x16x32_bf16(
                        af[i], bfr[j], acc[i][j], 0, 0, 0);
        }
        __syncthreads();
    }

    // C/D layout (m89): col = lane&15, row = (lane>>4)*4 + reg
    if (EPI == EPI_LOSS) {
        float* loss = (float*)Cout;
        const float inv_n = 1.0f / (float)N;
#pragma unroll
        for (int i = 0; i < 4; ++i) {
#pragma unroll
            for (int r = 0; r < 4; ++r) {
                const int row = row0 + wr + i * 16 + quad * 4 + r;
                const float D = P_NULL * __expf(bias[row]) + Saux[row];
                const float invD = 1.0f / D;
                float s = 0.f;
#pragma unroll
                for (int j = 0; j < 4; ++j) {
                    const int col = col0 + wc + j * 16 + tx;
                    const float d = acc[i][j][r] * invD - X[(size_t)row * N + col];
                    s = fmaf(d, d, s);
                }
                s += __shfl_xor(s, 1, 64);
                s += __shfl_xor(s, 2, 64);
                s += __shfl_xor(s, 4, 64);
                s += __shfl_xor(s, 8, 64);
                if (tx == 0) atomicAdd(&loss[row], s * inv_n);
            }
        }
    } else if (EPI == EPI_W || EPI == EPI_U) {
        u16* C = (u16*)Cout;
#pragma unroll
        for (int i = 0; i < 4; ++i) {
            float srow[4] = {0.f, 0.f, 0.f, 0.f};
#pragma unroll
            for (int j = 0; j < 4; ++j) {
                const int col = wc + j * 16 + tx;
                const float cb = bias[col0 + col];
#pragma unroll
                for (int r = 0; r < 4; ++r) {
                    const int row = wr + i * 16 + quad * 4 + r;
                    float w = __expf(fmaf(acc[i][j][r], alpha, -cb));
                    if (EPI == EPI_W)
                        w *= bf2f(Paux[(size_t)(row0 + row) * N + col0 + col]);
                    C[(size_t)(row0 + row) * N + col0 + col] = f2bf(w);
                    srow[r] += w;
                }
            }
#pragma unroll
            for (int r = 0; r < 4; ++r) {
                float s = srow[r];
                s += __shfl_xor(s, 1, 64);
                s += __shfl_xor(s, 2, 64);
                s += __shfl_xor(s, 4, 64);
                s += __shfl_xor(s, 8, 64);
                if (tx == 0)
                    atomicAdd(&Saux[row0 + wr + i * 16 + quad * 4 + r], s);
            }
        }
    } else {
        u16* C = (u16*)Cout;
#pragma unroll
        for (int i = 0; i < 4; ++i)
#pragma unroll
            for (int j = 0; j < 4; ++j) {
                const int col = wc + j * 16 + tx;
                const float b = bias[col0 + col];
#pragma unroll
                for (int r = 0; r < 4; ++r) {
                    const int row = wr + i * 16 + quad * 4 + r;
                    C[(size_t)(row0 + row) * N + col0 + col] =
                        f2bf(fmaf(acc[i][j][r], alpha, -b));
                }
            }
    }
}

// ---------------------------------------------------------------------------
// MFMA bf16 GEMM (64x128 tile) for the (B,E)-output GEMMs: 256 blocks.
// Optional per-row scale 1/Srow[row] (null -> no scale).
// ---------------------------------------------------------------------------
__global__ __launch_bounds__(256) void mfma_gemm64_kernel(
    const u16* __restrict__ A, const u16* __restrict__ Bm,
    u16* __restrict__ C, const float* __restrict__ Srow,
    int M, int N, int Kd) {
    __shared__ u16 As[64 * 64];
    __shared__ u16 Bs[128 * 64];
    const int tid = threadIdx.x;
    int btr, btc;
    swizzle_tiles(btr, btc);
    const int row0 = btr * 64, col0 = btc * 128;
    const int lane = tid & 63, wave = tid >> 6;
    const int wr = (wave >> 1) * 32, wc = (wave & 1) * 64;
    const int tx = lane & 15, quad = lane >> 4;
    const int txl = tx & 7;

    f32x4 acc[2][4] = {};

    for (int k0 = 0; k0 < Kd; k0 += 64) {
#pragma unroll
        for (int l = 0; l < 2; ++l) {
            const int lin = l * 2048 + tid * 8;
            const int r = lin >> 6;
            const int c = (((lin >> 3) & 7) ^ (r & 7)) * 8;
            gload_lds16(A + (size_t)(row0 + r) * Kd + k0 + c, &As[lin]);
        }
#pragma unroll
        for (int l = 0; l < 4; ++l) {
            const int lin = l * 2048 + tid * 8;
            const int r = lin >> 6;
            const int c = (((lin >> 3) & 7) ^ (r & 7)) * 8;
            gload_lds16(Bm + (size_t)(col0 + r) * Kd + k0 + c, &Bs[lin]);
        }
        __syncthreads();
#pragma unroll
        for (int ks = 0; ks < 2; ++ks) {
            bf16x8 af[2], bfr[4];
            const int gsw = ((ks * 4 + quad) ^ txl) * 8;
#pragma unroll
            for (int i = 0; i < 2; ++i)
                af[i] = *(const bf16x8*)&As[(wr + i * 16 + tx) * 64 + gsw];
#pragma unroll
            for (int j = 0; j < 4; ++j)
                bfr[j] = *(const bf16x8*)&Bs[(wc + j * 16 + tx) * 64 + gsw];
#pragma unroll
            for (int i = 0; i < 2; ++i)
#pragma unroll
                for (int j = 0; j < 4; ++j)
                    acc[i][j] = __builtin_amdgcn_mfma_f32_16x16x32_bf16(
                        af[i], bfr[j], acc[i][j], 0, 0, 0);
        }
        __syncthreads();
    }

#pragma unroll
    for (int i = 0; i < 2; ++i)
#pragma unroll
        for (int r = 0; r < 4; ++r) {
            const int row = row0 + wr + i * 16 + quad * 4 + r;
            const float sc = Srow ? (1.0f / Srow[row]) : 1.0f;
#pragma unroll
            for (int j = 0; j < 4; ++j) {
                const int col = col0 + wc + j * 16 + tx;
                C[(size_t)row * N + col] = f2bf(acc[i][j][r] * sc);
            }
        }
}

// ---------------------------------------------------------------------------
// Row softmax over K=2048 (bf16 in/out). One block (256 thr) per row.
// ---------------------------------------------------------------------------
__global__ __launch_bounds__(256) void softmax_bf_kernel(
    const u16* __restrict__ T, u16* __restrict__ P) {
    __shared__ float sm[4];
    const size_t base = (size_t)blockIdx.x * K + (size_t)threadIdx.x * 8;
    float v[8];
    unpack8(*(const uint4*)(T + base), v);
    float m = v[0];
#pragma unroll
    for (int i = 1; i < 8; ++i) m = fmaxf(m, v[i]);
    m = block_max256(m, sm);
    float s = 0.f;
#pragma unroll
    for (int i = 0; i < 8; ++i) {
        v[i] = __expf(v[i] - m);
        s += v[i];
    }
    s = block_sum256(s, sm);
    const float inv = 1.f / s;
#pragma unroll
    for (int i = 0; i < 8; ++i) v[i] *= inv;
    *(uint4*)(P + base) = pack8(v);
}

// ---------------------------------------------------------------------------
// Row mean of squares of Z (B,E) bf16: x2[row] = mean(Z[row,:]^2)
// ---------------------------------------------------------------------------
__global__ __launch_bounds__(256) void rowmeansq_bf_kernel(
    const u16* __restrict__ Z, float* __restrict__ out) {
    __shared__ float sm[4];
    const float v = bf2f(Z[(size_t)blockIdx.x * E + threadIdx.x]);
    const float s = block_sum256(v * v, sm);
    if (threadIdx.x == 0) out[blockIdx.x] = s * (1.0f / (float)E);
}

// ---------------------------------------------------------------------------
extern "C" void kernel_launch(void* const* d_in, const int* in_sizes, int n_in,
                              void* d_out, int out_size, void* d_ws, size_t ws_size,
                              hipStream_t stream) {
    const float* images = (const float*)d_in[0];  // (B,G)
    const float* xa     = (const float*)d_in[1];  // (G,K)
    const float* xb     = (const float*)d_in[2];  // (E,K)
    float* out = (float*)d_out;                   // (B,)

    // workspace carve-up (u16 elements, all regions 16B-aligned)
    u16* img_bf = (u16*)d_ws;                      // B*G
    u16* xa_bf  = img_bf + (size_t)B * G;          // G*K
    u16* xaT_bf = xa_bf + (size_t)G * K;           // K*G
    u16* xb_bf  = xaT_bf + (size_t)K * G;          // E*K
    u16* xbT_bf = xb_bf + (size_t)E * K;           // K*E
    u16* pik_bf = xbT_bf + (size_t)K * E;          // B*K
    u16* t_bf   = pik_bf + (size_t)B * K;          // B*K (encode logits)
    u16* w_bf   = t_bf + (size_t)B * K;            // B*K (loop w / decode u)
    u16* z_bf   = w_bf + (size_t)B * K;            // B*E
    float* c2a  = (float*)(z_bf + (size_t)B * E);  // K   --+ one memset
    float* c2b  = c2a + K;                         // K     |
    float* Svec = c2b + K;                         // 5*B --+ (S_w[0..3], S0)
    float* x2z  = Svec + 5 * B;                    // B (fully written)

    (void)hipMemsetAsync(d_out, 0, (size_t)B * sizeof(float), stream);
    (void)hipMemsetAsync(c2a, 0, (size_t)(2 * K + 5 * B) * sizeof(float), stream);

    // bf16 conversions + transposes
    f2bf_kernel<<<(B * G) / 2048, 256, 0, stream>>>(images, img_bf, B * G);
    f2bf_kernel<<<(G * K) / 2048, 256, 0, stream>>>(xa, xa_bf, G * K);
    f2bf_kernel<<<(E * K) / 2048, 256, 0, stream>>>(xb, xb_bf, E * K);
    transpose_bf_kernel<<<dim3(K / 32, G / 32), 256, 0, stream>>>(xa, xaT_bf, G, K);
    transpose_bf_kernel<<<dim3(K / 32, E / 32), 256, 0, stream>>>(xb, xbT_bf, E, K);

    // c2a[k] = mean_g xa[g,k]^2 ; c2b[k] = mean_e xb[e,k]^2
    colsq_kernel<<<dim3(K / 256, G / 128), 256, 0, stream>>>(xa, G, K, 1.0f / G, c2a);
    colsq_kernel<<<dim3(K / 256, E / 128), 256, 0, stream>>>(xb, E, K, 1.0f / E, c2b);

    // encode: t = images@xa * (2/G) - c2a ; pik = softmax(t)
    mfma_gemm_kernel<EPI_BIAS_BF16><<<dim3(K / 128, B / 128), 256, 0, stream>>>(
        img_bf, xaT_bf, t_bf, c2a, nullptr, nullptr, nullptr, B, K, G, 2.0f / (float)G);
    softmax_bf_kernel<<<B, 256, 0, stream>>>(t_bf, pik_bf);

    // z = pik @ xb^T
    mfma_gemm64_kernel<<<dim3(E / 128, B / 64), 256, 0, stream>>>(
        pik_bf, xb_bf, z_bf, nullptr, B, E, K);

    for (int s = 0; s < N_STEP; ++s) {
        float* Sw = Svec + (size_t)s * B;
        // w = pik*exp(z@xb*(2/E) - c2b) ; Sw[row] = sum_k w  (atomic)
        mfma_gemm_kernel<EPI_W><<<dim3(K / 128, B / 128), 256, 0, stream>>>(
            z_bf, xbT_bf, w_bf, c2b, nullptr, pik_bf, Sw, B, K, E, 2.0f / (float)E);
        // z = (w @ xb^T) / Sw[row]
        mfma_gemm64_kernel<<<dim3(E / 128, B / 64), 256, 0, stream>>>(
            w_bf, xb_bf, z_bf, Sw, B, E, K);
    }

    // decode: x2 = mean(z^2) ; u = exp(z@xb*(2/E) - c2b) ; S0[row] = sum u
    float* S0 = Svec + (size_t)4 * B;
    rowmeansq_bf_kernel<<<B, 256, 0, stream>>>(z_bf, x2z);
    mfma_gemm_kernel<EPI_U><<<dim3(K / 128, B / 128), 256, 0, stream>>>(
        z_bf, xbT_bf, w_bf, c2b, nullptr, nullptr, S0, B, K, E, 2.0f / (float)E);

    // loss: recon = (u @ xa^T)/D[row], D = P_NULL*e^{x2}+S0 ;
    // loss[b] = mean_g (recon - images)^2
    mfma_gemm_kernel<EPI_LOSS><<<dim3(G / 128, B / 128), 256, 0, stream>>>(
        w_bf, xa_bf, out, x2z, images, nullptr, S0, B, G, K, 1.0f);
}

// Round 9
// 562.369 us; speedup vs baseline: 1.7455x; 1.0016x over previous
//
#include <hip/hip_runtime.h>
#include <hip/hip_bf16.h>

// Problem constants (match reference)
constexpr int B = 8192;
constexpr int G = 1024;
constexpr int E = 256;
constexpr int K = 2048;
constexpr float P_NULL = 0.1f;
constexpr int N_STEP = 4;

typedef unsigned short u16;
typedef short bf16x8 __attribute__((ext_vector_type(8)));
typedef float f32x4 __attribute__((ext_vector_type(4)));

// ---------------------------------------------------------------------------
// bf16 <-> f32 (RNE)
// ---------------------------------------------------------------------------
__device__ inline u16 f2bf(float f) {
    union { float f; uint32_t u; } cv;
    cv.f = f;
    const uint32_t u = cv.u;
    return (u16)((u + 0x7fffu + ((u >> 16) & 1u)) >> 16);
}
__device__ inline float bf2f(u16 h) {
    union { uint32_t u; float f; } cv;
    cv.u = ((uint32_t)h) << 16;
    return cv.f;
}
__device__ inline void unpack8(uint4 u, float* v) {
    v[0] = bf2f((u16)(u.x & 0xffff)); v[1] = bf2f((u16)(u.x >> 16));
    v[2] = bf2f((u16)(u.y & 0xffff)); v[3] = bf2f((u16)(u.y >> 16));
    v[4] = bf2f((u16)(u.z & 0xffff)); v[5] = bf2f((u16)(u.z >> 16));
    v[6] = bf2f((u16)(u.w & 0xffff)); v[7] = bf2f((u16)(u.w >> 16));
}
__device__ inline uint4 pack8(const float* v) {
    uint4 u;
    u.x = (uint32_t)f2bf(v[0]) | ((uint32_t)f2bf(v[1]) << 16);
    u.y = (uint32_t)f2bf(v[2]) | ((uint32_t)f2bf(v[3]) << 16);
    u.z = (uint32_t)f2bf(v[4]) | ((uint32_t)f2bf(v[5]) << 16);
    u.w = (uint32_t)f2bf(v[6]) | ((uint32_t)f2bf(v[7]) << 16);
    return u;
}

// async global->LDS, 16B per lane (LDS dest is lane-linear; global src is
// per-lane and may be permuted -> XOR-swizzle is applied on the GLOBAL side)
typedef __attribute__((address_space(1))) const void* gaddr_t;
typedef __attribute__((address_space(3))) void* laddr_t;
__device__ inline void gload_lds16(const void* g, void* l) {
    __builtin_amdgcn_global_load_lds((gaddr_t)g, (laddr_t)l, 16, 0, 0);
}

// XCD-aware tile swizzle (requires gridDim.y % 8 == 0)
__device__ inline void swizzle_tiles(int& tr, int& tc) {
    const int cx = gridDim.x, cy = gridDim.y;
    const int id = blockIdx.y * cx + blockIdx.x;
    const int k = id & 7;
    const int q = id >> 3;
    tr = k * (cy >> 3) + q / cx;
    tc = q % cx;
}

// ---------------------------------------------------------------------------
// Reduction helpers (256-thread blocks, wave64)
// ---------------------------------------------------------------------------
__device__ inline float wave_sum(float v) {
#pragma unroll
    for (int off = 32; off > 0; off >>= 1) v += __shfl_down(v, off, 64);
    return v;
}
__device__ inline float wave_max(float v) {
#pragma unroll
    for (int off = 32; off > 0; off >>= 1) v = fmaxf(v, __shfl_down(v, off, 64));
    return v;
}
__device__ inline float block_sum256(float v, float* sm) {
    v = wave_sum(v);
    const int w = threadIdx.x >> 6;
    if ((threadIdx.x & 63) == 0) sm[w] = v;
    __syncthreads();
    const float r = sm[0] + sm[1] + sm[2] + sm[3];
    __syncthreads();
    return r;
}
__device__ inline float block_max256(float v, float* sm) {
    v = wave_max(v);
    const int w = threadIdx.x >> 6;
    if ((threadIdx.x & 63) == 0) sm[w] = v;
    __syncthreads();
    const float r = fmaxf(fmaxf(sm[0], sm[1]), fmaxf(sm[2], sm[3]));
    __syncthreads();
    return r;
}

// ---------------------------------------------------------------------------
// f32 -> bf16 flat convert, 8 elems/thread
// ---------------------------------------------------------------------------
__global__ __launch_bounds__(256) void f2bf_kernel(
    const float* __restrict__ in, u16* __restrict__ out, int n) {
    const int i = (blockIdx.x * 256 + threadIdx.x) * 8;
    if (i + 7 >= n) {
        for (int j = i; j < n; ++j) out[j] = f2bf(in[j]);
        return;
    }
    const float4 a = *(const float4*)(in + i);
    const float4 b = *(const float4*)(in + i + 4);
    float v[8] = {a.x, a.y, a.z, a.w, b.x, b.y, b.z, b.w};
    *(uint4*)(out + i) = pack8(v);
}

// ---------------------------------------------------------------------------
// Fused prep: f32 (R,C) -> bf16 (R,C) copy + bf16 (C,R) transpose +
// csq[c] += (1/R) sum_r v^2.  grid (C/32, R/32), block 256.
// ---------------------------------------------------------------------------
__global__ __launch_bounds__(256) void prep_kernel(
    const float* __restrict__ in, u16* __restrict__ outN,
    u16* __restrict__ outT, float* __restrict__ csq, int R, int C,
    float inv_R) {
    __shared__ float tile[32][33];
    __shared__ float sred[8][32];
    const int bx = blockIdx.x * 32, by = blockIdx.y * 32;
    const int x = threadIdx.x & 31, y0 = threadIdx.x >> 5;
    float s = 0.f;
#pragma unroll
    for (int yy = 0; yy < 32; yy += 8) {
        const float v = in[(size_t)(by + y0 + yy) * C + bx + x];
        tile[y0 + yy][x] = v;
        outN[(size_t)(by + y0 + yy) * C + bx + x] = f2bf(v);
        s = fmaf(v, v, s);
    }
    sred[y0][x] = s;
    __syncthreads();
#pragma unroll
    for (int yy = 0; yy < 32; yy += 8)
        outT[(size_t)(bx + y0 + yy) * R + by + x] = f2bf(tile[x][y0 + yy]);
    if (y0 == 0) {
        float t = 0.f;
#pragma unroll
        for (int k2 = 0; k2 < 8; ++k2) t += sred[k2][x];
        atomicAdd(csq + bx + x, t * inv_R);
    }
}

// ---------------------------------------------------------------------------
// MFMA bf16 GEMM (128x128 tile, BK=64): C = A(M,Kd) x Bm(N,Kd)^T
// Main-loop LDS XOR-swizzled (16B group g of row r at g^(r&7), applied on the
// GLOBAL source address) -> 0 bank conflicts (verified R7).
// Epilogues route the output tile through the freed As/Bs LDS (exactly 32KB =
// 128x128 bf16, XOR-16 swizzle) for vectorized 16B/lane global I/O:
//   EPI_BIAS_BF16: bf16 C = alpha*acc - bias[col]
//   EPI_W:  w = pik[row,col]*exp(alpha*acc - bias[col]); Saux[row] += sum(w)
//   EPI_U:  u = exp(alpha*acc - bias[col]); Saux[row] += sum(u)
//   EPI_LOSS: D = P_NULL*exp(bias[row]) + Saux[row];
//             loss[row] += (1/N)*sum_col (acc/D - X[row,col])^2
// ---------------------------------------------------------------------------
enum { EPI_BIAS_BF16 = 0, EPI_LOSS = 2, EPI_W = 3, EPI_U = 4 };

template <int EPI>
__global__ __launch_bounds__(256) void mfma_gemm_kernel(
    const u16* __restrict__ A, const u16* __restrict__ Bm,
    void* __restrict__ Cout, const float* __restrict__ bias,
    const float* __restrict__ X, const u16* __restrict__ Paux,
    float* __restrict__ Saux, int M, int N, int Kd, float alpha) {
    __shared__ u16 smem[16384];  // As | Bs during K-loop; 128x128 tile after
    u16* As = smem;
    u16* Bs = smem + 8192;
    const int tid = threadIdx.x;
    int btr, btc;
    swizzle_tiles(btr, btc);
    const int row0 = btr * 128, col0 = btc * 128;
    const int lane = tid & 63, wave = tid >> 6;
    const int wr = (wave >> 1) * 64, wc = (wave & 1) * 64;
    const int tx = lane & 15, quad = lane >> 4;
    const int txl = tx & 7;

    f32x4 acc[4][4] = {};

    for (int k0 = 0; k0 < Kd; k0 += 64) {
#pragma unroll
        for (int l = 0; l < 4; ++l) {
            const int lin = l * 2048 + tid * 8;
            const int r = lin >> 6;
            const int c = (((lin >> 3) & 7) ^ (r & 7)) * 8;  // XOR-swizzled src
            gload_lds16(A + (size_t)(row0 + r) * Kd + k0 + c, &As[lin]);
        }
#pragma unroll
        for (int l = 0; l < 4; ++l) {
            const int lin = l * 2048 + tid * 8;
            const int r = lin >> 6;
            const int c = (((lin >> 3) & 7) ^ (r & 7)) * 8;
            gload_lds16(Bm + (size_t)(col0 + r) * Kd + k0 + c, &Bs[lin]);
        }
        __syncthreads();
#pragma unroll
        for (int ks = 0; ks < 2; ++ks) {
            bf16x8 af[4], bfr[4];
            const int gsw = ((ks * 4 + quad) ^ txl) * 8;
#pragma unroll
            for (int i = 0; i < 4; ++i)
                af[i] = *(const bf16x8*)&As[(wr + i * 16 + tx) * 64 + gsw];
#pragma unroll
            for (int j = 0; j < 4; ++j)
                bfr[j] = *(const bf16x8*)&Bs[(wc + j * 16 + tx) * 64 + gsw];
#pragma unroll
            for (int i = 0; i < 4; ++i)
#pragma unroll
                for (int j = 0; j < 4; ++j)
                    acc[i][j] = __builtin_amdgcn_mfma_f32_16x16x32_bf16(
                        af[i], bfr[j], acc[i][j], 0, 0, 0);
        }
        __syncthreads();
    }

    // C/D layout (m89): col = lane&15, row = (lane>>4)*4 + reg
    if (EPI == EPI_LOSS) {
        float* loss = (float*)Cout;
        const float inv_n = 1.0f / (float)N;
#pragma unroll
        for (int i = 0; i < 4; ++i) {
#pragma unroll
            for (int r = 0; r < 4; ++r) {
                const int row = row0 + wr + i * 16 + quad * 4 + r;
                const float D = P_NULL * __expf(bias[row]) + Saux[row];
                const float invD = 1.0f / D;
                float s = 0.f;
#pragma unroll
                for (int j = 0; j < 4; ++j) {
                    const int col = col0 + wc + j * 16 + tx;
                    const float d = acc[i][j][r] * invD - X[(size_t)row * N + col];
                    s = fmaf(d, d, s);
                }
                s += __shfl_xor(s, 1, 64);
                s += __shfl_xor(s, 2, 64);
                s += __shfl_xor(s, 4, 64);
                s += __shfl_xor(s, 8, 64);
                if (tx == 0) atomicAdd(&loss[row], s * inv_n);
            }
        }
    } else {
        // ---- vectorized epilogue through LDS (tile = whole smem, XOR-16) ----
        if (EPI == EPI_W) {
            // stage pik tile (coalesced; group permutation on global side)
#pragma unroll
            for (int l = 0; l < 8; ++l) {
                const int lin = l * 2048 + tid * 8;
                const int r = lin >> 7;
                const int g = (lin >> 3) & 15;
                const int c = (g ^ (r & 15)) << 3;
                gload_lds16(Paux + (size_t)(row0 + r) * N + col0 + c, &smem[lin]);
            }
        }
        __syncthreads();  // staging visible / K-loop reads done before overwrite

        // phase 2: compute values, write tile to LDS (strided, XOR'd -> ~2-way)
#pragma unroll
        for (int i = 0; i < 4; ++i) {
            float srow[4] = {0.f, 0.f, 0.f, 0.f};
#pragma unroll
            for (int j = 0; j < 4; ++j) {
                const int pcol = wc + j * 16 + tx;
                const float cb = bias[col0 + pcol];
#pragma unroll
                for (int r = 0; r < 4; ++r) {
                    const int prow = wr + i * 16 + quad * 4 + r;
                    const int paddr = prow * 128 +
                        (((pcol >> 3) ^ (prow & 15)) << 3) + (pcol & 7);
                    float v;
                    if (EPI == EPI_BIAS_BF16) {
                        v = fmaf(acc[i][j][r], alpha, -cb);
                    } else {
                        v = __expf(fmaf(acc[i][j][r], alpha, -cb));
                        if (EPI == EPI_W) v *= bf2f(smem[paddr]);
                        srow[r] += v;
                    }
                    smem[paddr] = f2bf(v);
                }
            }
            if (EPI == EPI_W || EPI == EPI_U) {
#pragma unroll
                for (int r = 0; r < 4; ++r) {
                    float s = srow[r];
                    s += __shfl_xor(s, 1, 64);
                    s += __shfl_xor(s, 2, 64);
                    s += __shfl_xor(s, 4, 64);
                    s += __shfl_xor(s, 8, 64);
                    if (tx == 0)
                        atomicAdd(&Saux[row0 + wr + i * 16 + quad * 4 + r], s);
                }
            }
        }
        __syncthreads();

        // phase 3: vectorized store, 8 x uint4 per thread
        u16* C = (u16*)Cout;
        const int rr = tid >> 1, hs = tid & 1;
#pragma unroll
        for (int u = 0; u < 8; ++u) {
            const int gl = hs * 8 + u;
            const int pg = gl ^ (rr & 15);
            *(uint4*)(C + (size_t)(row0 + rr) * N + col0 + gl * 8) =
                *(const uint4*)&smem[rr * 128 + pg * 8];
        }
    }
}

// ---------------------------------------------------------------------------
// MFMA bf16 GEMM (64x128 tile) for the (B,E)-output GEMMs: 256 blocks.
// Optional per-row scale 1/Srow[row] (null -> no scale).
// ---------------------------------------------------------------------------
__global__ __launch_bounds__(256) void mfma_gemm64_kernel(
    const u16* __restrict__ A, const u16* __restrict__ Bm,
    u16* __restrict__ C, const float* __restrict__ Srow,
    int M, int N, int Kd) {
    __shared__ u16 As[64 * 64];
    __shared__ u16 Bs[128 * 64];
    const int tid = threadIdx.x;
    int btr, btc;
    swizzle_tiles(btr, btc);
    const int row0 = btr * 64, col0 = btc * 128;
    const int lane = tid & 63, wave = tid >> 6;
    const int wr = (wave >> 1) * 32, wc = (wave & 1) * 64;
    const int tx = lane & 15, quad = lane >> 4;
    const int txl = tx & 7;

    f32x4 acc[2][4] = {};

    for (int k0 = 0; k0 < Kd; k0 += 64) {
#pragma unroll
        for (int l = 0; l < 2; ++l) {
            const int lin = l * 2048 + tid * 8;
            const int r = lin >> 6;
            const int c = (((lin >> 3) & 7) ^ (r & 7)) * 8;
            gload_lds16(A + (size_t)(row0 + r) * Kd + k0 + c, &As[lin]);
        }
#pragma unroll
        for (int l = 0; l < 4; ++l) {
            const int lin = l * 2048 + tid * 8;
            const int r = lin >> 6;
            const int c = (((lin >> 3) & 7) ^ (r & 7)) * 8;
            gload_lds16(Bm + (size_t)(col0 + r) * Kd + k0 + c, &Bs[lin]);
        }
        __syncthreads();
#pragma unroll
        for (int ks = 0; ks < 2; ++ks) {
            bf16x8 af[2], bfr[4];
            const int gsw = ((ks * 4 + quad) ^ txl) * 8;
#pragma unroll
            for (int i = 0; i < 2; ++i)
                af[i] = *(const bf16x8*)&As[(wr + i * 16 + tx) * 64 + gsw];
#pragma unroll
            for (int j = 0; j < 4; ++j)
                bfr[j] = *(const bf16x8*)&Bs[(wc + j * 16 + tx) * 64 + gsw];
#pragma unroll
            for (int i = 0; i < 2; ++i)
#pragma unroll
                for (int j = 0; j < 4; ++j)
                    acc[i][j] = __builtin_amdgcn_mfma_f32_16x16x32_bf16(
                        af[i], bfr[j], acc[i][j], 0, 0, 0);
        }
        __syncthreads();
    }

#pragma unroll
    for (int i = 0; i < 2; ++i)
#pragma unroll
        for (int r = 0; r < 4; ++r) {
            const int row = row0 + wr + i * 16 + quad * 4 + r;
            const float sc = Srow ? (1.0f / Srow[row]) : 1.0f;
#pragma unroll
            for (int j = 0; j < 4; ++j) {
                const int col = col0 + wc + j * 16 + tx;
                C[(size_t)row * N + col] = f2bf(acc[i][j][r] * sc);
            }
        }
}

// ---------------------------------------------------------------------------
// Row softmax over K=2048 (bf16 in/out). One block (256 thr) per row.
// ---------------------------------------------------------------------------
__global__ __launch_bounds__(256) void softmax_bf_kernel(
    const u16* __restrict__ T, u16* __restrict__ P) {
    __shared__ float sm[4];
    const size_t base = (size_t)blockIdx.x * K + (size_t)threadIdx.x * 8;
    float v[8];
    unpack8(*(const uint4*)(T + base), v);
    float m = v[0];
#pragma unroll
    for (int i = 1; i < 8; ++i) m = fmaxf(m, v[i]);
    m = block_max256(m, sm);
    float s = 0.f;
#pragma unroll
    for (int i = 0; i < 8; ++i) {
        v[i] = __expf(v[i] - m);
        s += v[i];
    }
    s = block_sum256(s, sm);
    const float inv = 1.f / s;
#pragma unroll
    for (int i = 0; i < 8; ++i) v[i] *= inv;
    *(uint4*)(P + base) = pack8(v);
}

// ---------------------------------------------------------------------------
// Row mean of squares of Z (B,E) bf16: x2[row] = mean(Z[row,:]^2)
// ---------------------------------------------------------------------------
__global__ __launch_bounds__(256) void rowmeansq_bf_kernel(
    const u16* __restrict__ Z, float* __restrict__ out) {
    __shared__ float sm[4];
    const float v = bf2f(Z[(size_t)blockIdx.x * E + threadIdx.x]);
    const float s = block_sum256(v * v, sm);
    if (threadIdx.x == 0) out[blockIdx.x] = s * (1.0f / (float)E);
}

// ---------------------------------------------------------------------------
extern "C" void kernel_launch(void* const* d_in, const int* in_sizes, int n_in,
                              void* d_out, int out_size, void* d_ws, size_t ws_size,
                              hipStream_t stream) {
    const float* images = (const float*)d_in[0];  // (B,G)
    const float* xa     = (const float*)d_in[1];  // (G,K)
    const float* xb     = (const float*)d_in[2];  // (E,K)
    float* out = (float*)d_out;                   // (B,)

    // workspace carve-up (u16 elements, all regions 16B-aligned)
    u16* img_bf = (u16*)d_ws;                      // B*G
    u16* xa_bf  = img_bf + (size_t)B * G;          // G*K
    u16* xaT_bf = xa_bf + (size_t)G * K;           // K*G
    u16* xb_bf  = xaT_bf + (size_t)K * G;          // E*K
    u16* xbT_bf = xb_bf + (size_t)E * K;           // K*E
    u16* pik_bf = xbT_bf + (size_t)K * E;          // B*K
    u16* t_bf   = pik_bf + (size_t)B * K;          // B*K (encode logits)
    u16* w_bf   = t_bf + (size_t)B * K;            // B*K (loop w / decode u)
    u16* z_bf   = w_bf + (size_t)B * K;            // B*E
    float* c2a  = (float*)(z_bf + (size_t)B * E);  // K   --+ one memset
    float* c2b  = c2a + K;                         // K     |
    float* Svec = c2b + K;                         // 5*B --+ (S_w[0..3], S0)
    float* x2z  = Svec + 5 * B;                    // B (fully written)

    (void)hipMemsetAsync(d_out, 0, (size_t)B * sizeof(float), stream);
    (void)hipMemsetAsync(c2a, 0, (size_t)(2 * K + 5 * B) * sizeof(float), stream);

    // prep: bf16 copies + transposes + column mean-squares (one read each)
    f2bf_kernel<<<(B * G) / 2048, 256, 0, stream>>>(images, img_bf, B * G);
    prep_kernel<<<dim3(K / 32, G / 32), 256, 0, stream>>>(
        xa, xa_bf, xaT_bf, c2a, G, K, 1.0f / (float)G);
    prep_kernel<<<dim3(K / 32, E / 32), 256, 0, stream>>>(
        xb, xb_bf, xbT_bf, c2b, E, K, 1.0f / (float)E);

    // encode: t = images@xa * (2/G) - c2a ; pik = softmax(t)
    mfma_gemm_kernel<EPI_BIAS_BF16><<<dim3(K / 128, B / 128), 256, 0, stream>>>(
        img_bf, xaT_bf, t_bf, c2a, nullptr, nullptr, nullptr, B, K, G, 2.0f / (float)G);
    softmax_bf_kernel<<<B, 256, 0, stream>>>(t_bf, pik_bf);

    // z = pik @ xb^T
    mfma_gemm64_kernel<<<dim3(E / 128, B / 64), 256, 0, stream>>>(
        pik_bf, xb_bf, z_bf, nullptr, B, E, K);

    for (int s = 0; s < N_STEP; ++s) {
        float* Sw = Svec + (size_t)s * B;
        // w = pik*exp(z@xb*(2/E) - c2b) ; Sw[row] = sum_k w  (atomic)
        mfma_gemm_kernel<EPI_W><<<dim3(K / 128, B / 128), 256, 0, stream>>>(
            z_bf, xbT_bf, w_bf, c2b, nullptr, pik_bf, Sw, B, K, E, 2.0f / (float)E);
        // z = (w @ xb^T) / Sw[row]
        mfma_gemm64_kernel<<<dim3(E / 128, B / 64), 256, 0, stream>>>(
            w_bf, xb_bf, z_bf, Sw, B, E, K);
    }

    // decode: x2 = mean(z^2) ; u = exp(z@xb*(2/E) - c2b) ; S0[row] = sum u
    float* S0 = Svec + (size_t)4 * B;
    rowmeansq_bf_kernel<<<B, 256, 0, stream>>>(z_bf, x2z);
    mfma_gemm_kernel<EPI_U><<<dim3(K / 128, B / 128), 256, 0, stream>>>(
        z_bf, xbT_bf, w_bf, c2b, nullptr, nullptr, S0, B, K, E, 2.0f / (float)E);

    // loss: recon = (u @ xa^T)/D[row], D = P_NULL*e^{x2}+S0 ;
    // loss[b] = mean_g (recon - images)^2
    mfma_gemm_kernel<EPI_LOSS><<<dim3(G / 128, B / 128), 256, 0, stream>>>(
        w_bf, xa_bf, out, x2z, images, nullptr, S0, B, G, K, 1.0f);
}